// Round 9
// baseline (333.514 us; speedup 1.0000x reference)
//
#include <hip/hip_runtime.h>
#include <hip/hip_bf16.h>

#define NB  8
#define NC  256
#define NCK 64
#define SEQ 2048

typedef unsigned short u16;
typedef short bfrag8 __attribute__((ext_vector_type(8)));   // 8 bf16 (4 VGPRs)
typedef float ffrag4 __attribute__((ext_vector_type(4)));   // 4 fp32 acc

#define MFMA16(a, b, c) __builtin_amdgcn_mfma_f32_16x16x32_bf16((a), (b), (c), 0, 0, 0)

static __device__ __forceinline__ u16 f2bf(float f) {
  return __builtin_bit_cast(u16, (__bf16)f);  // RNE
}
static __device__ __forceinline__ float bf2f(u16 u) {
  unsigned v = (unsigned)u << 16;
  return __builtin_bit_cast(float, v);
}

// ---------- W fp32 -> bf16 hi/lo; last block zeroes ssum/sqsum ----------
__global__ __launch_bounds__(256) void wconv_kernel(
    const float* __restrict__ Wq, const float* __restrict__ Wv,
    const float* __restrict__ Wt, const float* __restrict__ Wk,
    u16* __restrict__ dst, float* __restrict__ zz) {
  int id = blockIdx.x * 256 + threadIdx.x;
  if (blockIdx.x == 832) {
    if (threadIdx.x < 256) { zz[threadIdx.x] = 0.f; zz[256 + threadIdx.x] = 0.f; }
    return;
  }
  const float* src;
  int off, seg;
  if (id < 65536)       { src = Wq; off = 0;      seg = 65536; }
  else if (id < 131072) { src = Wv; off = 131072; seg = 65536; id -= 65536; }
  else if (id < 196608) { src = Wt; off = 262144; seg = 65536; id -= 131072; }
  else                  { src = Wk; off = 393216; seg = 16384; id -= 196608; }
  float v = src[id];
  u16 h = f2bf(v);
  u16 l = f2bf(v - bf2f(h));
  dst[off + id] = h;
  dst[off + seg + id] = l;
}

// ---------- transpose-convert: in fp32 [b][CIN][n] -> Thi/Tlo bf16 [b][n][CIN] ----------
template <int CIN>
__global__ __launch_bounds__(256) void tconv_kernel(
    const float* __restrict__ in, u16* __restrict__ Thi, u16* __restrict__ Tlo) {
  __shared__ float t[32][33];
  const int tid = threadIdx.x;
  const int b = blockIdx.x & 7, cg = blockIdx.x >> 3;
  const int c0 = cg << 5, n0 = blockIdx.y << 5;
  {
    int c = tid >> 3, m4 = (tid & 7) << 2;
    float4 v = *(const float4*)&in[((size_t)b * CIN + c0 + c) * SEQ + n0 + m4];
    t[c][m4 + 0] = v.x; t[c][m4 + 1] = v.y; t[c][m4 + 2] = v.z; t[c][m4 + 3] = v.w;
  }
  __syncthreads();
  {
    int n = tid >> 3, c4 = (tid & 7) << 2;
    u16 h[4], l[4];
#pragma unroll
    for (int j = 0; j < 4; ++j) {
      float v = t[c4 + j][n];
      h[j] = f2bf(v);
      l[j] = f2bf(v - bf2f(h[j]));
    }
    size_t base = ((size_t)b * SEQ + n0 + n) * CIN + c0 + c4;
    *(uint2*)&Thi[base] = make_uint2((unsigned)h[0] | ((unsigned)h[1] << 16),
                                     (unsigned)h[2] | ((unsigned)h[3] << 16));
    *(uint2*)&Tlo[base] = make_uint2((unsigned)l[0] | ((unsigned)l[1] << 16),
                                     (unsigned)l[2] | ((unsigned)l[3] << 16));
  }
}

// ---------- MFMA GEMM v2, hi/lo split (3-pass). act: [b][n][K] hi/lo; W: [256][K] hi/lo.
// Block = 128n x 64o; wave = 32n (2 rowsets) x 64o -> 6 MFMA per 2 LDS reads.
// WA=0: out bf16 [b][n][256]. WA=1: out [b][o][n], bf16 or fp32 (+bias).
// OUTF32 additionally accumulates BatchNorm partial sums into ssum/sqsum.
template <int K, bool WA, bool OUTF32>
__global__ __launch_bounds__(256, 2) void gemm_kernel(
    const u16* __restrict__ Ahi, const u16* __restrict__ Alo,
    const u16* __restrict__ Whi, const u16* __restrict__ Wlo,
    const float* __restrict__ bias, void* __restrict__ outp,
    float* __restrict__ ssum, float* __restrict__ sqsum) {
  constexpr int SP = K + 8;
  extern __shared__ u16 lds[];  // 64*SP*2 shorts (hi rows then lo rows)
  static __shared__ float bsum[64], bsq[64];
  const int tid = threadIdx.x;
  const int wv = tid >> 6, lane = tid & 63, quad = lane >> 4, ln = lane & 15;
  const int b = blockIdx.x & 7, nt = blockIdx.x >> 3;
  const int o0 = blockIdx.y << 6, n0 = nt << 7;

  if (WA && OUTF32 && tid < 64) { bsum[tid] = 0.f; bsq[tid] = 0.f; }

  constexpr int RW = K / 8;
  for (int i = tid; i < 64 * RW; i += 256) {
    int row = i / RW, kc = (i % RW) * 8;
    *(uint4*)&lds[row * SP + kc] = *(const uint4*)&Whi[(size_t)(o0 + row) * K + kc];
    *(uint4*)&lds[(64 + row) * SP + kc] = *(const uint4*)&Wlo[(size_t)(o0 + row) * K + kc];
  }
  constexpr int NA = K / 32;
  bfrag8 ahi[2][NA], alo[2][NA];
#pragma unroll
  for (int rs = 0; rs < 2; ++rs) {
    const u16* ap = Ahi + ((size_t)b * SEQ + n0 + wv * 32 + rs * 16 + ln) * K + quad * 8;
    const u16* al = Alo + ((size_t)b * SEQ + n0 + wv * 32 + rs * 16 + ln) * K + quad * 8;
#pragma unroll
    for (int a = 0; a < NA; ++a) {
      ahi[rs][a] = *(const bfrag8*)(ap + a * 32);
      alo[rs][a] = *(const bfrag8*)(al + a * 32);
    }
  }
  __syncthreads();

  ffrag4 acc[2][4];
#pragma unroll
  for (int ot = 0; ot < 4; ++ot) {
    ffrag4 e0 = {0.f, 0.f, 0.f, 0.f}, e1 = {0.f, 0.f, 0.f, 0.f};
#pragma unroll
    for (int a = 0; a < NA; ++a) {
      bfrag8 wh = *(const bfrag8*)&lds[(ot * 16 + ln) * SP + a * 32 + quad * 8];
      bfrag8 wl = *(const bfrag8*)&lds[(64 + ot * 16 + ln) * SP + a * 32 + quad * 8];
      if (WA) {
        e0 = MFMA16(wh, ahi[0][a], e0);
        e0 = MFMA16(wh, alo[0][a], e0);
        e0 = MFMA16(wl, ahi[0][a], e0);
        e1 = MFMA16(wh, ahi[1][a], e1);
        e1 = MFMA16(wh, alo[1][a], e1);
        e1 = MFMA16(wl, ahi[1][a], e1);
      } else {
        e0 = MFMA16(ahi[0][a], wh, e0);
        e0 = MFMA16(alo[0][a], wh, e0);
        e0 = MFMA16(ahi[0][a], wl, e0);
        e1 = MFMA16(ahi[1][a], wh, e1);
        e1 = MFMA16(alo[1][a], wh, e1);
        e1 = MFMA16(ahi[1][a], wl, e1);
      }
    }
    acc[0][ot] = e0;
    acc[1][ot] = e1;
  }
  __syncthreads();  // lds free for epilogue

  if (!WA) {
    u16* tl = lds;  // [128 n][72]
#pragma unroll
    for (int rs = 0; rs < 2; ++rs)
#pragma unroll
      for (int ot = 0; ot < 4; ++ot)
#pragma unroll
        for (int r = 0; r < 4; ++r)
          tl[(wv * 32 + rs * 16 + quad * 4 + r) * 72 + ot * 16 + ln] = f2bf(acc[rs][ot][r]);
    __syncthreads();
    u16* out = (u16*)outp;
    for (int i = tid; i < 128 * 8; i += 256) {
      int row = i >> 3, c8 = (i & 7) * 8;
      *(uint4*)&out[((size_t)b * SEQ + n0 + row) * NC + o0 + c8] = *(uint4*)&tl[row * 72 + c8];
    }
  } else {
    float* fl = (float*)lds;  // [64 o][132]
#pragma unroll
    for (int rs = 0; rs < 2; ++rs)
#pragma unroll
      for (int ot = 0; ot < 4; ++ot)
#pragma unroll
        for (int r = 0; r < 4; ++r)
          fl[(ot * 16 + quad * 4 + r) * 132 + wv * 32 + rs * 16 + ln] = acc[rs][ot][r];
    __syncthreads();
    for (int i = tid; i < 64 * 32; i += 256) {
      int row = i >> 5, n4 = (i & 31) * 4;
      float bb = (bias != nullptr) ? bias[o0 + row] : 0.f;
      const float* src = &fl[row * 132 + n4];
      if (OUTF32) {
        float4 v = *(const float4*)src;
        v.x += bb; v.y += bb; v.z += bb; v.w += bb;
        *(float4*)&((float*)outp)[((size_t)b * NC + o0 + row) * SEQ + n0 + n4] = v;
        float s = v.x + v.y + v.z + v.w;
        float sq = v.x * v.x + v.y * v.y + v.z * v.z + v.w * v.w;
        atomicAdd(&bsum[row], s);
        atomicAdd(&bsq[row], sq);
      } else {
        uint2 pk;
        pk.x = (unsigned)f2bf(src[0] + bb) | ((unsigned)f2bf(src[1] + bb) << 16);
        pk.y = (unsigned)f2bf(src[2] + bb) | ((unsigned)f2bf(src[3] + bb) << 16);
        *(uint2*)&((u16*)outp)[((size_t)b * NC + o0 + row) * SEQ + n0 + n4] = pk;
      }
    }
    if (OUTF32) {
      __syncthreads();
      if (tid < 64) {
        atomicAdd(&ssum[o0 + tid], bsum[tid]);
        atomicAdd(&sqsum[o0 + tid], bsq[tid]);
      }
    }
  }
}

// ---------- rowsum: rowsum_g[b,n] += sum_m exp(e[n,m]) over this block's 512-m quarter ----------
__global__ __launch_bounds__(256, 2) void rowsum_kernel(
    const u16* __restrict__ xqT, const u16* __restrict__ xkT,
    float* __restrict__ rowsum_g) {
  __shared__ u16 bk_l[2][64 * 264];  // 2 x 33792 B
  const int tid = threadIdx.x;
  const int wv = tid >> 6, lane = tid & 63, quad = lane >> 4, ln = lane & 15;
  const int b  = blockIdx.x & 7;
  const int nt = (blockIdx.x >> 3) & 15;
  const int mh = blockIdx.x >> 7;   // 0..3
  const int n0 = nt << 7;
  const int m0 = mh << 9;

  bfrag8 aq[2][8];
#pragma unroll
  for (int rs = 0; rs < 2; ++rs) {
    const u16* qp = xqT + ((size_t)b * SEQ + n0 + wv * 32 + rs * 16 + ln) * NC + quad * 8;
#pragma unroll
    for (int kk = 0; kk < 8; ++kk) aq[rs][kk] = *(const bfrag8*)(qp + kk * 32);
  }

  const int srow = tid >> 2, sseg = tid & 3;
  uint4 pf[8];
  {
    const u16* kp = xkT + ((size_t)b * SEQ + m0 + srow) * NC;
#pragma unroll
    for (int j = 0; j < 8; ++j) pf[j] = *(const uint4*)&kp[(sseg + 4 * j) * 8];
  }

  float rsum[2][4];
#pragma unroll
  for (int rs = 0; rs < 2; ++rs)
#pragma unroll
    for (int r = 0; r < 4; ++r) rsum[rs][r] = 0.f;

  for (int ch = 0; ch < 8; ++ch) {
    u16* buf = bk_l[ch & 1];
#pragma unroll
    for (int j = 0; j < 8; ++j) *(uint4*)&buf[srow * 264 + (sseg + 4 * j) * 8] = pf[j];
    if (ch < 7) {
      const u16* kp = xkT + ((size_t)b * SEQ + m0 + (ch + 1) * 64 + srow) * NC;
#pragma unroll
      for (int j = 0; j < 8; ++j) pf[j] = *(const uint4*)&kp[(sseg + 4 * j) * 8];
    }
    __syncthreads();

    ffrag4 e[2][4];
#pragma unroll
    for (int rs = 0; rs < 2; ++rs)
#pragma unroll
      for (int ms = 0; ms < 4; ++ms) e[rs][ms] = (ffrag4){0.f, 0.f, 0.f, 0.f};
#pragma unroll
    for (int ms = 0; ms < 4; ++ms)
#pragma unroll
      for (int kk = 0; kk < 8; ++kk) {
        bfrag8 bf = *(const bfrag8*)&buf[(ms * 16 + ln) * 264 + kk * 32 + quad * 8];
        e[0][ms] = MFMA16(aq[0][kk], bf, e[0][ms]);
        e[1][ms] = MFMA16(aq[1][kk], bf, e[1][ms]);
      }
#pragma unroll
    for (int rs = 0; rs < 2; ++rs)
#pragma unroll
      for (int ms = 0; ms < 4; ++ms)
#pragma unroll
        for (int r = 0; r < 4; ++r) rsum[rs][r] += __expf(e[rs][ms][r]);
  }

#pragma unroll
  for (int msk = 1; msk < 16; msk <<= 1)
#pragma unroll
    for (int rs = 0; rs < 2; ++rs)
#pragma unroll
      for (int r = 0; r < 4; ++r) rsum[rs][r] += __shfl_xor(rsum[rs][r], msk, 64);
  if (ln == 0) {
#pragma unroll
    for (int rs = 0; rs < 2; ++rs)
#pragma unroll
      for (int r = 0; r < 4; ++r)
        atomicAdd(&rowsum_g[(size_t)b * SEQ + n0 + wv * 32 + rs * 16 + quad * 4 + r],
                  rsum[rs][r]);
  }
}

// ---------- attn v3: 64-n tiles per barrier pair; U (bf16) + csum partials ----------
__global__ __launch_bounds__(512, 4) void attn_kernel(
    const u16* __restrict__ xqT, const u16* __restrict__ xkT,
    const u16* __restrict__ xv, const float* __restrict__ rowsum_g,
    u16* __restrict__ U, float* __restrict__ csum) {
  __shared__ u16 xq_l[64 * 264];  // 33792 B
  __shared__ u16 p_l[64 * 72];    // 9216 B, rows 144 B (16B-aligned for b128)
  __shared__ float ri_l[64];
  __shared__ float cs_l[64];
  const int tid = threadIdx.x;
  const int wv = tid >> 6, lane = tid & 63, quad = lane >> 4, ln = lane & 15;
  const int b = blockIdx.x & 7;
  const int m0 = ((blockIdx.x >> 3) & 31) << 6;
  const int half = blockIdx.x >> 8;
  const int msub = wv >> 1, nlo = wv & 1;
  const int it0 = half * 16, itEnd = it0 + 16;  // n0 = it*64

  if (tid < 64) cs_l[tid] = 0.f;

  // persistent energy B-frags: keys m0 + msub*16 + ln, K=256
  bfrag8 bk[8];
  {
    const u16* kp = xkT + ((size_t)b * SEQ + m0 + msub * 16 + ln) * NC + quad * 8;
#pragma unroll
    for (int kk = 0; kk < 8; ++kk) bk[kk] = *(const bfrag8*)(kp + kk * 32);
  }

  // prefetch: 64-row xq tile (64 B/thread) + rowsum
  const int prow = tid >> 3, pcol = (tid & 7) << 5;
  uint4 pf[4];
  float rspf = 1.f;
  {
    const u16* src = &xqT[((size_t)b * SEQ + it0 * 64 + prow) * NC + pcol];
#pragma unroll
    for (int j = 0; j < 4; ++j) pf[j] = *(const uint4*)(src + 8 * j);
    if (tid < 64) rspf = rowsum_g[(size_t)b * SEQ + it0 * 64 + tid];
  }

  ffrag4 acc[2][4];
#pragma unroll
  for (int ct = 0; ct < 2; ++ct)
#pragma unroll
    for (int s = 0; s < 4; ++s) acc[ct][s] = (ffrag4){0.f, 0.f, 0.f, 0.f};
  float cs = 0.f;

  for (int it = it0; it < itEnd; ++it) {
    const int n0 = it << 6;
    // commit prefetched xq tile + rowinv
#pragma unroll
    for (int j = 0; j < 4; ++j) *(uint4*)&xq_l[prow * 264 + pcol + 8 * j] = pf[j];
    if (tid < 64) ri_l[tid] = 1.0f / rspf;
    // issue next iteration's prefetch
    {
      const int itn = (it + 1 < itEnd) ? it + 1 : it;
      const u16* src = &xqT[((size_t)b * SEQ + itn * 64 + prow) * NC + pcol];
#pragma unroll
      for (int j = 0; j < 4; ++j) pf[j] = *(const uint4*)(src + 8 * j);
      if (tid < 64) rspf = rowsum_g[(size_t)b * SEQ + itn * 64 + tid];
    }
    // issue this iteration's xv A-frags (consumed after E)
    bfrag8 av[2][2];
#pragma unroll
    for (int ct = 0; ct < 2; ++ct)
#pragma unroll
      for (int g = 0; g < 2; ++g)
        av[ct][g] = *(const bfrag8*)&xv[((size_t)b * NC + wv * 32 + ct * 16 + ln) * SEQ +
                                        n0 + g * 32 + quad * 8];
    __syncthreads();
    // E-phase: 2 tasks per wave (nsub2 = nlo*2 + j)
#pragma unroll
    for (int j = 0; j < 2; ++j) {
      const int ns = nlo * 2 + j;
      ffrag4 e = {0.f, 0.f, 0.f, 0.f};
#pragma unroll
      for (int kk = 0; kk < 8; ++kk) {
        bfrag8 a = *(const bfrag8*)&xq_l[(ns * 16 + ln) * 264 + kk * 32 + quad * 8];
        e = MFMA16(a, bk[kk], e);
      }
      u16 pu[4];
#pragma unroll
      for (int r = 0; r < 4; ++r) {
        float p = __expf(e[r]) * ri_l[ns * 16 + quad * 4 + r];
        cs += p;
        pu[r] = f2bf(p);
      }
      *(uint2*)&p_l[(msub * 16 + ln) * 72 + ns * 16 + quad * 4] =
          make_uint2((unsigned)pu[0] | ((unsigned)pu[1] << 16),
                     (unsigned)pu[2] | ((unsigned)pu[3] << 16));
    }
    __syncthreads();
    // PV: K=64 (both 32-n groups)
#pragma unroll
    for (int s = 0; s < 4; ++s) {
      bfrag8 pb0 = *(const bfrag8*)&p_l[(s * 16 + ln) * 72 + quad * 8];
      bfrag8 pb1 = *(const bfrag8*)&p_l[(s * 16 + ln) * 72 + 32 + quad * 8];
      acc[0][s] = MFMA16(av[0][0], pb0, acc[0][s]);
      acc[0][s] = MFMA16(av[0][1], pb1, acc[0][s]);
      acc[1][s] = MFMA16(av[1][0], pb0, acc[1][s]);
      acc[1][s] = MFMA16(av[1][1], pb1, acc[1][s]);
    }
  }

  cs += __shfl_down(cs, 32, 64);
  cs += __shfl_down(cs, 16, 64);
  if (lane < 16) atomicAdd(&cs_l[msub * 16 + ln], cs);
  __syncthreads();
  if (tid < 64) csum[((size_t)half * NB + b) * SEQ + m0 + tid] = cs_l[tid];

  u16* Uh = U + (size_t)half * NB * NC * SEQ;
#pragma unroll
  for (int ct = 0; ct < 2; ++ct)
#pragma unroll
    for (int s = 0; s < 4; ++s)
#pragma unroll
      for (int r = 0; r < 4; ++r)
        Uh[((size_t)b * NC + wv * 32 + ct * 16 + quad * 4 + r) * SEQ + m0 + s * 16 + ln] =
            f2bf(acc[ct][s][r]);
}

// ---------- combine: xrT_hi/lo [b][m][c] = bf16 split of (U0+U1)[c][m]/(1e-9+colsum[m]) ----------
__global__ __launch_bounds__(256) void combine_kernel(
    const u16* __restrict__ U, const float* __restrict__ csum,
    u16* __restrict__ xrT_hi, u16* __restrict__ xrT_lo) {
  __shared__ float t[32][33];
  __shared__ float im[32];
  const int tid = threadIdx.x;
  const int b = blockIdx.x & 7, cg = blockIdx.x >> 3;
  const int c0 = cg << 5, m0 = blockIdx.y << 5;
  const size_t SZi = (size_t)NB * NC * SEQ;

  if (tid < 32)
    im[tid] = 1.0f / (1e-9f + csum[(size_t)b * SEQ + m0 + tid] +
                      csum[((size_t)NB + b) * SEQ + m0 + tid]);
  __syncthreads();
  {
    int c = tid >> 3, m4 = (tid & 7) << 2;
    size_t idx = ((size_t)b * NC + c0 + c) * SEQ + m0 + m4;
    uint2 a0 = *(const uint2*)&U[idx];
    uint2 a1 = *(const uint2*)&U[SZi + idx];
    const u16* p0 = (const u16*)&a0;
    const u16* p1 = (const u16*)&a1;
#pragma unroll
    for (int j = 0; j < 4; ++j)
      t[c][m4 + j] = (bf2f(p0[j]) + bf2f(p1[j])) * im[m4 + j];
  }
  __syncthreads();
  {
    int m = tid >> 3, c4 = (tid & 7) << 2;
    u16 h[4], l[4];
#pragma unroll
    for (int j = 0; j < 4; ++j) {
      float v = t[c4 + j][m];
      h[j] = f2bf(v);
      l[j] = f2bf(v - bf2f(h[j]));
    }
    size_t base = ((size_t)b * SEQ + m0 + m) * NC + c0 + c4;
    *(uint2*)&xrT_hi[base] = make_uint2((unsigned)h[0] | ((unsigned)h[1] << 16),
                                        (unsigned)h[2] | ((unsigned)h[3] << 16));
    *(uint2*)&xrT_lo[base] = make_uint2((unsigned)l[0] | ((unsigned)l[1] << 16),
                                        (unsigned)l[2] | ((unsigned)l[3] << 16));
  }
}

// ---------- BN normalize + ReLU ----------
__global__ __launch_bounds__(256) void bnorm_kernel(
    const float* __restrict__ y, const float* __restrict__ ssum, const float* __restrict__ sqsum,
    const float* __restrict__ gamma, const float* __restrict__ beta, float* __restrict__ out) {
  size_t e0 = ((size_t)blockIdx.x * 256 + threadIdx.x) * 4;
  int o = (int)((e0 >> 11) & (NC - 1));
  const float invn = 1.0f / 16384.0f;
  float mean = ssum[o] * invn;
  float var = sqsum[o] * invn - mean * mean;
  float rs = rsqrtf(var + 1e-5f);
  float a = gamma[o] * rs;
  float c = beta[o] - mean * a;
  float4 v = *(const float4*)(y + e0);
  float4 r;
  r.x = fmaxf(0.f, fmaf(v.x, a, c));
  r.y = fmaxf(0.f, fmaf(v.y, a, c));
  r.z = fmaxf(0.f, fmaf(v.z, a, c));
  r.w = fmaxf(0.f, fmaf(v.w, a, c));
  *(float4*)(out + e0) = r;
}

extern "C" void kernel_launch(void* const* d_in, const int* in_sizes, int n_in,
                              void* d_out, int out_size, void* d_ws, size_t ws_size,
                              hipStream_t stream) {
  const float* q     = (const float*)d_in[0];
  const float* x     = (const float*)d_in[1];
  const float* Wq    = (const float*)d_in[2];
  const float* Wk    = (const float*)d_in[3];
  const float* Wv    = (const float*)d_in[4];
  const float* bv    = (const float*)d_in[5];
  const float* Wt    = (const float*)d_in[6];
  const float* bt    = (const float*)d_in[7];
  const float* gamma = (const float*)d_in[8];
  const float* beta  = (const float*)d_in[9];
  float* out = (float*)d_out;

  // Arena (phase-overlaid). SZ = 4,194,304 elems; SZB = 16 MB.
  const size_t SZ = (size_t)NB * NC * SEQ;
  const size_t SZB = SZ * 4;
  char* wsb = (char*)d_ws;
  u16* qT_hi = (u16*)(wsb);                 // [B][N][256] bf16
  u16* qT_lo = qT_hi + SZ;
  u16* xT_hi = (u16*)(wsb + SZB);           // [B][N][64] bf16
  u16* xT_lo = xT_hi + SZ / 4;
  u16* U     = (u16*)(wsb);                 // [2][B][C][N] bf16 (overlays qT/xT after gemms)
  u16* xqT = (u16*)(wsb + 2 * SZB);         // [B][N][256] bf16
  u16* xkT = xqT + SZ;                      // [B][M][256] bf16
  u16* xrT_hi = xqT;                        // reuse after attn
  u16* xrT_lo = xkT;
  u16* xv = (u16*)(wsb + 3 * SZB);          // [B][C][N] bf16
  float* y = (float*)(wsb);                 // [B][C][N] fp32 (overlays U after combine)
  u16* wpack = (u16*)(wsb + 3 * SZB + SZB / 2);
  u16* Wq_hi = wpack,          *Wq_lo = wpack + 65536;
  u16* Wv_hi = wpack + 131072, *Wv_lo = wpack + 196608;
  u16* Wt_hi = wpack + 262144, *Wt_lo = wpack + 327680;
  u16* Wk_hi = wpack + 393216, *Wk_lo = wpack + 409600;
  float* rowsum_g = (float*)(wpack + 425984);     // [B][SEQ]
  float* csum = rowsum_g + (size_t)NB * SEQ;      // [2][B][SEQ]
  float* ssum = csum + 2 * (size_t)NB * SEQ;      // [256]
  float* sqsum = ssum + NC;                       // [256]

  hipMemsetAsync(rowsum_g, 0, (size_t)NB * SEQ * sizeof(float), stream);

  wconv_kernel<<<833, 256, 0, stream>>>(Wq, Wv, Wt, Wk, wpack, ssum);
  tconv_kernel<NC><<<dim3(64, 64), 256, 0, stream>>>(q, qT_hi, qT_lo);
  tconv_kernel<NCK><<<dim3(16, 64), 256, 0, stream>>>(x, xT_hi, xT_lo);

  const size_t shm256 = 64 * (256 + 8) * 2 * sizeof(u16);  // 67,584 B
  const size_t shm64  = 64 * (64 + 8) * 2 * sizeof(u16);   // 18,432 B
  gemm_kernel<256, false, false><<<dim3(128, 4), 256, shm256, stream>>>(
      qT_hi, qT_lo, Wq_hi, Wq_lo, nullptr, xqT, nullptr, nullptr);
  gemm_kernel<64, false, false><<<dim3(128, 4), 256, shm64, stream>>>(
      xT_hi, xT_lo, Wk_hi, Wk_lo, nullptr, xkT, nullptr, nullptr);
  gemm_kernel<256, true, false><<<dim3(128, 4), 256, shm256, stream>>>(
      qT_hi, qT_lo, Wv_hi, Wv_lo, bv, xv, nullptr, nullptr);

  rowsum_kernel<<<512, 256, 0, stream>>>(xqT, xkT, rowsum_g);
  attn_kernel<<<512, 512, 0, stream>>>(xqT, xkT, xv, rowsum_g, U, csum);
  combine_kernel<<<dim3(64, 64), 256, 0, stream>>>(U, csum, xrT_hi, xrT_lo);

  gemm_kernel<256, true, true><<<dim3(128, 4), 256, shm256, stream>>>(
      xrT_hi, xrT_lo, Wt_hi, Wt_lo, bt, y, ssum, sqsum);

  bnorm_kernel<<<4096, 256, 0, stream>>>(y, ssum, sqsum, gamma, beta, out);
}

// Round 10
// 272.421 us; speedup vs baseline: 1.2243x; 1.2243x over previous
//
#include <hip/hip_runtime.h>
#include <hip/hip_bf16.h>

#define NB  8
#define NC  256
#define NCK 64
#define SEQ 2048

typedef unsigned short u16;
typedef short bfrag8 __attribute__((ext_vector_type(8)));   // 8 bf16 (4 VGPRs)
typedef float ffrag4 __attribute__((ext_vector_type(4)));   // 4 fp32 acc

#define MFMA16(a, b, c) __builtin_amdgcn_mfma_f32_16x16x32_bf16((a), (b), (c), 0, 0, 0)

static __device__ __forceinline__ u16 f2bf(float f) {
  return __builtin_bit_cast(u16, (__bf16)f);  // RNE
}
static __device__ __forceinline__ float bf2f(u16 u) {
  unsigned v = (unsigned)u << 16;
  return __builtin_bit_cast(float, v);
}

// ---------- W fp32 -> bf16 hi/lo; last block zeroes ssum/sqsum ----------
__global__ __launch_bounds__(256) void wconv_kernel(
    const float* __restrict__ Wq, const float* __restrict__ Wv,
    const float* __restrict__ Wt, const float* __restrict__ Wk,
    u16* __restrict__ dst, float* __restrict__ zz) {
  int id = blockIdx.x * 256 + threadIdx.x;
  if (blockIdx.x == 832) {
    if (threadIdx.x < 256) { zz[threadIdx.x] = 0.f; zz[256 + threadIdx.x] = 0.f; }
    return;
  }
  const float* src;
  int off, seg;
  if (id < 65536)       { src = Wq; off = 0;      seg = 65536; }
  else if (id < 131072) { src = Wv; off = 131072; seg = 65536; id -= 65536; }
  else if (id < 196608) { src = Wt; off = 262144; seg = 65536; id -= 131072; }
  else                  { src = Wk; off = 393216; seg = 16384; id -= 196608; }
  float v = src[id];
  u16 h = f2bf(v);
  u16 l = f2bf(v - bf2f(h));
  dst[off + id] = h;
  dst[off + seg + id] = l;
}

// ---------- transpose-convert: in fp32 [b][CIN][n] -> Thi/Tlo bf16 [b][n][CIN] ----------
template <int CIN>
__global__ __launch_bounds__(256) void tconv_kernel(
    const float* __restrict__ in, u16* __restrict__ Thi, u16* __restrict__ Tlo) {
  __shared__ float t[32][33];
  const int tid = threadIdx.x;
  const int b = blockIdx.x & 7, cg = blockIdx.x >> 3;
  const int c0 = cg << 5, n0 = blockIdx.y << 5;
  {
    int c = tid >> 3, m4 = (tid & 7) << 2;
    float4 v = *(const float4*)&in[((size_t)b * CIN + c0 + c) * SEQ + n0 + m4];
    t[c][m4 + 0] = v.x; t[c][m4 + 1] = v.y; t[c][m4 + 2] = v.z; t[c][m4 + 3] = v.w;
  }
  __syncthreads();
  {
    int n = tid >> 3, c4 = (tid & 7) << 2;
    u16 h[4], l[4];
#pragma unroll
    for (int j = 0; j < 4; ++j) {
      float v = t[c4 + j][n];
      h[j] = f2bf(v);
      l[j] = f2bf(v - bf2f(h[j]));
    }
    size_t base = ((size_t)b * SEQ + n0 + n) * CIN + c0 + c4;
    *(uint2*)&Thi[base] = make_uint2((unsigned)h[0] | ((unsigned)h[1] << 16),
                                     (unsigned)h[2] | ((unsigned)h[3] << 16));
    *(uint2*)&Tlo[base] = make_uint2((unsigned)l[0] | ((unsigned)l[1] << 16),
                                     (unsigned)l[2] | ((unsigned)l[3] << 16));
  }
}

// ---------- MFMA GEMM v2, hi/lo split (3-pass). act: [b][n][K] hi/lo; W: [256][K] hi/lo.
// Block = 128n x 64o; wave = 32n (2 rowsets) x 64o -> 6 MFMA per 2 LDS reads.
// WA=0: out bf16 [b][n][256]. WA=1: out [b][o][n], bf16 or fp32 (+bias).
// OUTF32 additionally accumulates BatchNorm partial sums into ssum/sqsum.
template <int K, bool WA, bool OUTF32>
__global__ __launch_bounds__(256, 2) void gemm_kernel(
    const u16* __restrict__ Ahi, const u16* __restrict__ Alo,
    const u16* __restrict__ Whi, const u16* __restrict__ Wlo,
    const float* __restrict__ bias, void* __restrict__ outp,
    float* __restrict__ ssum, float* __restrict__ sqsum) {
  constexpr int SP = K + 8;
  extern __shared__ u16 lds[];  // 64*SP*2 shorts (hi rows then lo rows)
  static __shared__ float bsum[64], bsq[64];
  const int tid = threadIdx.x;
  const int wv = tid >> 6, lane = tid & 63, quad = lane >> 4, ln = lane & 15;
  const int b = blockIdx.x & 7, nt = blockIdx.x >> 3;
  const int o0 = blockIdx.y << 6, n0 = nt << 7;

  if (WA && OUTF32 && tid < 64) { bsum[tid] = 0.f; bsq[tid] = 0.f; }

  constexpr int RW = K / 8;
  for (int i = tid; i < 64 * RW; i += 256) {
    int row = i / RW, kc = (i % RW) * 8;
    *(uint4*)&lds[row * SP + kc] = *(const uint4*)&Whi[(size_t)(o0 + row) * K + kc];
    *(uint4*)&lds[(64 + row) * SP + kc] = *(const uint4*)&Wlo[(size_t)(o0 + row) * K + kc];
  }
  constexpr int NA = K / 32;
  bfrag8 ahi[2][NA], alo[2][NA];
#pragma unroll
  for (int rs = 0; rs < 2; ++rs) {
    const u16* ap = Ahi + ((size_t)b * SEQ + n0 + wv * 32 + rs * 16 + ln) * K + quad * 8;
    const u16* al = Alo + ((size_t)b * SEQ + n0 + wv * 32 + rs * 16 + ln) * K + quad * 8;
#pragma unroll
    for (int a = 0; a < NA; ++a) {
      ahi[rs][a] = *(const bfrag8*)(ap + a * 32);
      alo[rs][a] = *(const bfrag8*)(al + a * 32);
    }
  }
  __syncthreads();

  ffrag4 acc[2][4];
#pragma unroll
  for (int ot = 0; ot < 4; ++ot) {
    ffrag4 e0 = {0.f, 0.f, 0.f, 0.f}, e1 = {0.f, 0.f, 0.f, 0.f};
#pragma unroll
    for (int a = 0; a < NA; ++a) {
      bfrag8 wh = *(const bfrag8*)&lds[(ot * 16 + ln) * SP + a * 32 + quad * 8];
      bfrag8 wl = *(const bfrag8*)&lds[(64 + ot * 16 + ln) * SP + a * 32 + quad * 8];
      if (WA) {
        e0 = MFMA16(wh, ahi[0][a], e0);
        e0 = MFMA16(wh, alo[0][a], e0);
        e0 = MFMA16(wl, ahi[0][a], e0);
        e1 = MFMA16(wh, ahi[1][a], e1);
        e1 = MFMA16(wh, alo[1][a], e1);
        e1 = MFMA16(wl, ahi[1][a], e1);
      } else {
        e0 = MFMA16(ahi[0][a], wh, e0);
        e0 = MFMA16(alo[0][a], wh, e0);
        e0 = MFMA16(ahi[0][a], wl, e0);
        e1 = MFMA16(ahi[1][a], wh, e1);
        e1 = MFMA16(alo[1][a], wh, e1);
        e1 = MFMA16(ahi[1][a], wl, e1);
      }
    }
    acc[0][ot] = e0;
    acc[1][ot] = e1;
  }
  __syncthreads();  // lds free for epilogue

  if (!WA) {
    u16* tl = lds;  // [128 n][72]
#pragma unroll
    for (int rs = 0; rs < 2; ++rs)
#pragma unroll
      for (int ot = 0; ot < 4; ++ot)
#pragma unroll
        for (int r = 0; r < 4; ++r)
          tl[(wv * 32 + rs * 16 + quad * 4 + r) * 72 + ot * 16 + ln] = f2bf(acc[rs][ot][r]);
    __syncthreads();
    u16* out = (u16*)outp;
    for (int i = tid; i < 128 * 8; i += 256) {
      int row = i >> 3, c8 = (i & 7) * 8;
      *(uint4*)&out[((size_t)b * SEQ + n0 + row) * NC + o0 + c8] = *(uint4*)&tl[row * 72 + c8];
    }
  } else {
    float* fl = (float*)lds;  // [64 o][132]
#pragma unroll
    for (int rs = 0; rs < 2; ++rs)
#pragma unroll
      for (int ot = 0; ot < 4; ++ot)
#pragma unroll
        for (int r = 0; r < 4; ++r)
          fl[(ot * 16 + quad * 4 + r) * 132 + wv * 32 + rs * 16 + ln] = acc[rs][ot][r];
    __syncthreads();
    for (int i = tid; i < 64 * 32; i += 256) {
      int row = i >> 5, n4 = (i & 31) * 4;
      float bb = (bias != nullptr) ? bias[o0 + row] : 0.f;
      const float* src = &fl[row * 132 + n4];
      if (OUTF32) {
        float4 v = *(const float4*)src;
        v.x += bb; v.y += bb; v.z += bb; v.w += bb;
        *(float4*)&((float*)outp)[((size_t)b * NC + o0 + row) * SEQ + n0 + n4] = v;
        float s = v.x + v.y + v.z + v.w;
        float sq = v.x * v.x + v.y * v.y + v.z * v.z + v.w * v.w;
        atomicAdd(&bsum[row], s);
        atomicAdd(&bsq[row], sq);
      } else {
        uint2 pk;
        pk.x = (unsigned)f2bf(src[0] + bb) | ((unsigned)f2bf(src[1] + bb) << 16);
        pk.y = (unsigned)f2bf(src[2] + bb) | ((unsigned)f2bf(src[3] + bb) << 16);
        *(uint2*)&((u16*)outp)[((size_t)b * NC + o0 + row) * SEQ + n0 + n4] = pk;
      }
    }
    if (OUTF32) {
      __syncthreads();
      if (tid < 64) {
        atomicAdd(&ssum[o0 + tid], bsum[tid]);
        atomicAdd(&sqsum[o0 + tid], bsq[tid]);
      }
    }
  }
}

// ---------- rowsum: rowsum_g[b,n] += sum_m exp(e[n,m]) over this block's 512-m quarter ----------
__global__ __launch_bounds__(256, 2) void rowsum_kernel(
    const u16* __restrict__ xqT, const u16* __restrict__ xkT,
    float* __restrict__ rowsum_g) {
  __shared__ u16 bk_l[2][64 * 264];  // 2 x 33792 B
  const int tid = threadIdx.x;
  const int wv = tid >> 6, lane = tid & 63, quad = lane >> 4, ln = lane & 15;
  const int b  = blockIdx.x & 7;
  const int nt = (blockIdx.x >> 3) & 15;
  const int mh = blockIdx.x >> 7;   // 0..3
  const int n0 = nt << 7;
  const int m0 = mh << 9;

  bfrag8 aq[2][8];
#pragma unroll
  for (int rs = 0; rs < 2; ++rs) {
    const u16* qp = xqT + ((size_t)b * SEQ + n0 + wv * 32 + rs * 16 + ln) * NC + quad * 8;
#pragma unroll
    for (int kk = 0; kk < 8; ++kk) aq[rs][kk] = *(const bfrag8*)(qp + kk * 32);
  }

  const int srow = tid >> 2, sseg = tid & 3;
  uint4 pf[8];
  {
    const u16* kp = xkT + ((size_t)b * SEQ + m0 + srow) * NC;
#pragma unroll
    for (int j = 0; j < 8; ++j) pf[j] = *(const uint4*)&kp[(sseg + 4 * j) * 8];
  }

  float rsum[2][4];
#pragma unroll
  for (int rs = 0; rs < 2; ++rs)
#pragma unroll
    for (int r = 0; r < 4; ++r) rsum[rs][r] = 0.f;

  for (int ch = 0; ch < 8; ++ch) {
    u16* buf = bk_l[ch & 1];
#pragma unroll
    for (int j = 0; j < 8; ++j) *(uint4*)&buf[srow * 264 + (sseg + 4 * j) * 8] = pf[j];
    if (ch < 7) {
      const u16* kp = xkT + ((size_t)b * SEQ + m0 + (ch + 1) * 64 + srow) * NC;
#pragma unroll
      for (int j = 0; j < 8; ++j) pf[j] = *(const uint4*)&kp[(sseg + 4 * j) * 8];
    }
    __syncthreads();

    ffrag4 e[2][4];
#pragma unroll
    for (int rs = 0; rs < 2; ++rs)
#pragma unroll
      for (int ms = 0; ms < 4; ++ms) e[rs][ms] = (ffrag4){0.f, 0.f, 0.f, 0.f};
#pragma unroll
    for (int ms = 0; ms < 4; ++ms)
#pragma unroll
      for (int kk = 0; kk < 8; ++kk) {
        bfrag8 bf = *(const bfrag8*)&buf[(ms * 16 + ln) * 264 + kk * 32 + quad * 8];
        e[0][ms] = MFMA16(aq[0][kk], bf, e[0][ms]);
        e[1][ms] = MFMA16(aq[1][kk], bf, e[1][ms]);
      }
#pragma unroll
    for (int rs = 0; rs < 2; ++rs)
#pragma unroll
      for (int ms = 0; ms < 4; ++ms)
#pragma unroll
        for (int r = 0; r < 4; ++r) rsum[rs][r] += __expf(e[rs][ms][r]);
  }

#pragma unroll
  for (int msk = 1; msk < 16; msk <<= 1)
#pragma unroll
    for (int rs = 0; rs < 2; ++rs)
#pragma unroll
      for (int r = 0; r < 4; ++r) rsum[rs][r] += __shfl_xor(rsum[rs][r], msk, 64);
  if (ln == 0) {
#pragma unroll
    for (int rs = 0; rs < 2; ++rs)
#pragma unroll
      for (int r = 0; r < 4; ++r)
        atomicAdd(&rowsum_g[(size_t)b * SEQ + n0 + wv * 32 + rs * 16 + quad * 4 + r],
                  rsum[rs][r]);
  }
}

// ---------- attn (R8-proven, register-prefetched): U (bf16) + csum partials ----------
__global__ __launch_bounds__(512, 4) void attn_kernel(
    const u16* __restrict__ xqT, const u16* __restrict__ xkT,
    const u16* __restrict__ xv, const float* __restrict__ rowsum_g,
    u16* __restrict__ U, float* __restrict__ csum) {
  __shared__ u16 xq_l[32 * 264];
  __shared__ u16 p_l[64 * 36];
  __shared__ float ri_l[32];
  __shared__ float cs_l[64];
  const int tid = threadIdx.x;
  const int wv = tid >> 6, lane = tid & 63, quad = lane >> 4, ln = lane & 15;
  const int b = blockIdx.x & 7;
  const int m0 = ((blockIdx.x >> 3) & 31) << 6;
  const int half = blockIdx.x >> 8;
  const int nsub = wv & 1, msub = wv >> 1;
  const int nt0 = half * 32, ntEnd = nt0 + 32;

  if (tid < 64) cs_l[tid] = 0.f;

  // persistent energy B-frags: keys m0 + msub*16 + ln, K=256
  bfrag8 bk[8];
  {
    const u16* kp = xkT + ((size_t)b * SEQ + m0 + msub * 16 + ln) * NC + quad * 8;
#pragma unroll
    for (int kk = 0; kk < 8; ++kk) bk[kk] = *(const bfrag8*)(kp + kk * 32);
  }

  // prefetch state: xq tile (32B/thread), rowsum, and this wave's xv frags
  const int prow = tid >> 4, pcol = (tid & 15) << 4;
  uint4 pf0, pf1;
  float rspf = 1.f;
  bfrag8 avpf0, avpf1;
  {
    const int n0 = nt0 << 5;
    const u16* src = &xqT[((size_t)b * SEQ + n0 + prow) * NC + pcol];
    pf0 = *(const uint4*)src;
    pf1 = *(const uint4*)(src + 8);
    if (tid < 32) rspf = rowsum_g[(size_t)b * SEQ + n0 + tid];
    const u16* vp = &xv[((size_t)b * NC + wv * 32 + ln) * SEQ + n0 + quad * 8];
    avpf0 = *(const bfrag8*)vp;
    avpf1 = *(const bfrag8*)(vp + 16 * SEQ);
  }

  ffrag4 acc[2][4];
#pragma unroll
  for (int ct = 0; ct < 2; ++ct)
#pragma unroll
    for (int s = 0; s < 4; ++s) acc[ct][s] = (ffrag4){0.f, 0.f, 0.f, 0.f};
  float cs = 0.f;

  for (int nt = nt0; nt < ntEnd; ++nt) {
    // (a) commit prefetched data to LDS / regs
    bfrag8 av0 = avpf0, av1 = avpf1;
    *(uint4*)&xq_l[prow * 264 + pcol] = pf0;
    *(uint4*)&xq_l[prow * 264 + pcol + 8] = pf1;
    if (tid < 32) ri_l[tid] = 1.0f / rspf;
    // (b) issue next iteration's loads
    {
      const int ntn = (nt + 1 < ntEnd) ? nt + 1 : nt;
      const int n0n = ntn << 5;
      const u16* src = &xqT[((size_t)b * SEQ + n0n + prow) * NC + pcol];
      pf0 = *(const uint4*)src;
      pf1 = *(const uint4*)(src + 8);
      if (tid < 32) rspf = rowsum_g[(size_t)b * SEQ + n0n + tid];
      const u16* vp = &xv[((size_t)b * NC + wv * 32 + ln) * SEQ + n0n + quad * 8];
      avpf0 = *(const bfrag8*)vp;
      avpf1 = *(const bfrag8*)(vp + 16 * SEQ);
    }
    __syncthreads();
    // (d) E-phase
    {
      ffrag4 e = {0.f, 0.f, 0.f, 0.f};
#pragma unroll
      for (int kk = 0; kk < 8; ++kk) {
        bfrag8 a = *(const bfrag8*)&xq_l[(nsub * 16 + ln) * 264 + kk * 32 + quad * 8];
        e = MFMA16(a, bk[kk], e);
      }
      u16 pu[4];
#pragma unroll
      for (int r = 0; r < 4; ++r) {
        float p = __expf(e[r]) * ri_l[nsub * 16 + quad * 4 + r];
        cs += p;
        pu[r] = f2bf(p);
      }
      *(uint2*)&p_l[(msub * 16 + ln) * 36 + nsub * 16 + quad * 4] =
          make_uint2((unsigned)pu[0] | ((unsigned)pu[1] << 16),
                     (unsigned)pu[2] | ((unsigned)pu[3] << 16));
    }
    __syncthreads();
    // (f) PV
    union PB { uint2 u2[2]; bfrag8 f; };
    PB pb[4];
#pragma unroll
    for (int s = 0; s < 4; ++s) {
      pb[s].u2[0] = *(const uint2*)&p_l[(s * 16 + ln) * 36 + quad * 8];
      pb[s].u2[1] = *(const uint2*)&p_l[(s * 16 + ln) * 36 + quad * 8 + 4];
    }
#pragma unroll
    for (int s = 0; s < 4; ++s) {
      acc[0][s] = MFMA16(av0, pb[s].f, acc[0][s]);
      acc[1][s] = MFMA16(av1, pb[s].f, acc[1][s]);
    }
  }

  cs += __shfl_down(cs, 32, 64);
  cs += __shfl_down(cs, 16, 64);
  if (lane < 16) atomicAdd(&cs_l[msub * 16 + ln], cs);
  __syncthreads();
  if (tid < 64) csum[((size_t)half * NB + b) * SEQ + m0 + tid] = cs_l[tid];

  u16* Uh = U + (size_t)half * NB * NC * SEQ;
#pragma unroll
  for (int ct = 0; ct < 2; ++ct)
#pragma unroll
    for (int s = 0; s < 4; ++s)
#pragma unroll
      for (int r = 0; r < 4; ++r)
        Uh[((size_t)b * NC + wv * 32 + ct * 16 + quad * 4 + r) * SEQ + m0 + s * 16 + ln] =
            f2bf(acc[ct][s][r]);
}

// ---------- combine: xrT_hi/lo [b][m][c] = bf16 split of (U0+U1)[c][m]/(1e-9+colsum[m]) ----------
__global__ __launch_bounds__(256) void combine_kernel(
    const u16* __restrict__ U, const float* __restrict__ csum,
    u16* __restrict__ xrT_hi, u16* __restrict__ xrT_lo) {
  __shared__ float t[32][33];
  __shared__ float im[32];
  const int tid = threadIdx.x;
  const int b = blockIdx.x & 7, cg = blockIdx.x >> 3;
  const int c0 = cg << 5, m0 = blockIdx.y << 5;
  const size_t SZi = (size_t)NB * NC * SEQ;

  if (tid < 32)
    im[tid] = 1.0f / (1e-9f + csum[(size_t)b * SEQ + m0 + tid] +
                      csum[((size_t)NB + b) * SEQ + m0 + tid]);
  __syncthreads();
  {
    int c = tid >> 3, m4 = (tid & 7) << 2;
    size_t idx = ((size_t)b * NC + c0 + c) * SEQ + m0 + m4;
    uint2 a0 = *(const uint2*)&U[idx];
    uint2 a1 = *(const uint2*)&U[SZi + idx];
    const u16* p0 = (const u16*)&a0;
    const u16* p1 = (const u16*)&a1;
#pragma unroll
    for (int j = 0; j < 4; ++j)
      t[c][m4 + j] = (bf2f(p0[j]) + bf2f(p1[j])) * im[m4 + j];
  }
  __syncthreads();
  {
    int m = tid >> 3, c4 = (tid & 7) << 2;
    u16 h[4], l[4];
#pragma unroll
    for (int j = 0; j < 4; ++j) {
      float v = t[c4 + j][m];
      h[j] = f2bf(v);
      l[j] = f2bf(v - bf2f(h[j]));
    }
    size_t base = ((size_t)b * SEQ + m0 + m) * NC + c0 + c4;
    *(uint2*)&xrT_hi[base] = make_uint2((unsigned)h[0] | ((unsigned)h[1] << 16),
                                        (unsigned)h[2] | ((unsigned)h[3] << 16));
    *(uint2*)&xrT_lo[base] = make_uint2((unsigned)l[0] | ((unsigned)l[1] << 16),
                                        (unsigned)l[2] | ((unsigned)l[3] << 16));
  }
}

// ---------- BN normalize + ReLU ----------
__global__ __launch_bounds__(256) void bnorm_kernel(
    const float* __restrict__ y, const float* __restrict__ ssum, const float* __restrict__ sqsum,
    const float* __restrict__ gamma, const float* __restrict__ beta, float* __restrict__ out) {
  size_t e0 = ((size_t)blockIdx.x * 256 + threadIdx.x) * 4;
  int o = (int)((e0 >> 11) & (NC - 1));
  const float invn = 1.0f / 16384.0f;
  float mean = ssum[o] * invn;
  float var = sqsum[o] * invn - mean * mean;
  float rs = rsqrtf(var + 1e-5f);
  float a = gamma[o] * rs;
  float c = beta[o] - mean * a;
  float4 v = *(const float4*)(y + e0);
  float4 r;
  r.x = fmaxf(0.f, fmaf(v.x, a, c));
  r.y = fmaxf(0.f, fmaf(v.y, a, c));
  r.z = fmaxf(0.f, fmaf(v.z, a, c));
  r.w = fmaxf(0.f, fmaf(v.w, a, c));
  *(float4*)(out + e0) = r;
}

extern "C" void kernel_launch(void* const* d_in, const int* in_sizes, int n_in,
                              void* d_out, int out_size, void* d_ws, size_t ws_size,
                              hipStream_t stream) {
  const float* q     = (const float*)d_in[0];
  const float* x     = (const float*)d_in[1];
  const float* Wq    = (const float*)d_in[2];
  const float* Wk    = (const float*)d_in[3];
  const float* Wv    = (const float*)d_in[4];
  const float* bv    = (const float*)d_in[5];
  const float* Wt    = (const float*)d_in[6];
  const float* bt    = (const float*)d_in[7];
  const float* gamma = (const float*)d_in[8];
  const float* beta  = (const float*)d_in[9];
  float* out = (float*)d_out;

  // Arena (phase-overlaid). SZ = 4,194,304 elems; SZB = 16 MB.
  const size_t SZ = (size_t)NB * NC * SEQ;
  const size_t SZB = SZ * 4;
  char* wsb = (char*)d_ws;
  u16* qT_hi = (u16*)(wsb);                 // [B][N][256] bf16
  u16* qT_lo = qT_hi + SZ;
  u16* xT_hi = (u16*)(wsb + SZB);           // [B][N][64] bf16
  u16* xT_lo = xT_hi + SZ / 4;
  u16* U     = (u16*)(wsb);                 // [2][B][C][N] bf16 (overlays qT/xT after gemms)
  u16* xqT = (u16*)(wsb + 2 * SZB);         // [B][N][256] bf16
  u16* xkT = xqT + SZ;                      // [B][M][256] bf16
  u16* xrT_hi = xqT;                        // reuse after attn
  u16* xrT_lo = xkT;
  u16* xv = (u16*)(wsb + 3 * SZB);          // [B][C][N] bf16
  float* y = (float*)(wsb);                 // [B][C][N] fp32 (overlays U after combine)
  u16* wpack = (u16*)(wsb + 3 * SZB + SZB / 2);
  u16* Wq_hi = wpack,          *Wq_lo = wpack + 65536;
  u16* Wv_hi = wpack + 131072, *Wv_lo = wpack + 196608;
  u16* Wt_hi = wpack + 262144, *Wt_lo = wpack + 327680;
  u16* Wk_hi = wpack + 393216, *Wk_lo = wpack + 409600;
  float* rowsum_g = (float*)(wpack + 425984);     // [B][SEQ]
  float* csum = rowsum_g + (size_t)NB * SEQ;      // [2][B][SEQ]
  float* ssum = csum + 2 * (size_t)NB * SEQ;      // [256]
  float* sqsum = ssum + NC;                       // [256]

  hipMemsetAsync(rowsum_g, 0, (size_t)NB * SEQ * sizeof(float), stream);

  wconv_kernel<<<833, 256, 0, stream>>>(Wq, Wv, Wt, Wk, wpack, ssum);
  tconv_kernel<NC><<<dim3(64, 64), 256, 0, stream>>>(q, qT_hi, qT_lo);
  tconv_kernel<NCK><<<dim3(16, 64), 256, 0, stream>>>(x, xT_hi, xT_lo);

  const size_t shm256 = 64 * (256 + 8) * 2 * sizeof(u16);  // 67,584 B
  const size_t shm64  = 64 * (64 + 8) * 2 * sizeof(u16);   // 18,432 B
  gemm_kernel<256, false, false><<<dim3(128, 4), 256, shm256, stream>>>(
      qT_hi, qT_lo, Wq_hi, Wq_lo, nullptr, xqT, nullptr, nullptr);
  gemm_kernel<64, false, false><<<dim3(128, 4), 256, shm64, stream>>>(
      xT_hi, xT_lo, Wk_hi, Wk_lo, nullptr, xkT, nullptr, nullptr);
  gemm_kernel<256, true, false><<<dim3(128, 4), 256, shm256, stream>>>(
      qT_hi, qT_lo, Wv_hi, Wv_lo, bv, xv, nullptr, nullptr);

  rowsum_kernel<<<512, 256, 0, stream>>>(xqT, xkT, rowsum_g);
  attn_kernel<<<512, 512, 0, stream>>>(xqT, xkT, xv, rowsum_g, U, csum);
  combine_kernel<<<dim3(64, 64), 256, 0, stream>>>(U, csum, xrT_hi, xrT_lo);

  gemm_kernel<256, true, true><<<dim3(128, 4), 256, shm256, stream>>>(
      xrT_hi, xrT_lo, Wt_hi, Wt_lo, bt, y, ssum, sqsum);

  bnorm_kernel<<<4096, 256, 0, stream>>>(y, ssum, sqsum, gamma, beta, out);
}

// Round 11
// 266.898 us; speedup vs baseline: 1.2496x; 1.0207x over previous
//
#include <hip/hip_runtime.h>
#include <hip/hip_bf16.h>

#define NB  8
#define NC  256
#define NCK 64
#define SEQ 2048

typedef unsigned short u16;
typedef short bfrag8 __attribute__((ext_vector_type(8)));   // 8 bf16 (4 VGPRs)
typedef float ffrag4 __attribute__((ext_vector_type(4)));   // 4 fp32 acc

#define MFMA16(a, b, c) __builtin_amdgcn_mfma_f32_16x16x32_bf16((a), (b), (c), 0, 0, 0)

static __device__ __forceinline__ u16 f2bf(float f) {
  return __builtin_bit_cast(u16, (__bf16)f);  // RNE
}
static __device__ __forceinline__ float bf2f(u16 u) {
  unsigned v = (unsigned)u << 16;
  return __builtin_bit_cast(float, v);
}

// ---------- W fp32 -> bf16 hi/lo; tail blocks zero ssum/sqsum and rowsum_g ----------
__global__ __launch_bounds__(256) void wconv_kernel(
    const float* __restrict__ Wq, const float* __restrict__ Wv,
    const float* __restrict__ Wt, const float* __restrict__ Wk,
    u16* __restrict__ dst, float* __restrict__ zz, float* __restrict__ rowsum_g) {
  int id = blockIdx.x * 256 + threadIdx.x;
  if (blockIdx.x >= 832) {
    if (blockIdx.x == 832) {
      zz[threadIdx.x] = 0.f;
      zz[256 + threadIdx.x] = 0.f;
    } else {
      rowsum_g[(blockIdx.x - 833) * 256 + threadIdx.x] = 0.f;
    }
    return;
  }
  const float* src;
  int off, seg;
  if (id < 65536)       { src = Wq; off = 0;      seg = 65536; }
  else if (id < 131072) { src = Wv; off = 131072; seg = 65536; id -= 65536; }
  else if (id < 196608) { src = Wt; off = 262144; seg = 65536; id -= 131072; }
  else                  { src = Wk; off = 393216; seg = 16384; id -= 196608; }
  float v = src[id];
  u16 h = f2bf(v);
  u16 l = f2bf(v - bf2f(h));
  dst[off + id] = h;
  dst[off + seg + id] = l;
}

// ---------- transpose-convert: in fp32 [b][CIN][n] -> Thi/Tlo bf16 [b][n][CIN] ----------
template <int CIN>
__global__ __launch_bounds__(256) void tconv_kernel(
    const float* __restrict__ in, u16* __restrict__ Thi, u16* __restrict__ Tlo) {
  __shared__ float t[32][33];
  const int tid = threadIdx.x;
  const int b = blockIdx.x & 7, cg = blockIdx.x >> 3;
  const int c0 = cg << 5, n0 = blockIdx.y << 5;
  {
    int c = tid >> 3, m4 = (tid & 7) << 2;
    float4 v = *(const float4*)&in[((size_t)b * CIN + c0 + c) * SEQ + n0 + m4];
    t[c][m4 + 0] = v.x; t[c][m4 + 1] = v.y; t[c][m4 + 2] = v.z; t[c][m4 + 3] = v.w;
  }
  __syncthreads();
  {
    int n = tid >> 3, c4 = (tid & 7) << 2;
    u16 h[4], l[4];
#pragma unroll
    for (int j = 0; j < 4; ++j) {
      float v = t[c4 + j][n];
      h[j] = f2bf(v);
      l[j] = f2bf(v - bf2f(h[j]));
    }
    size_t base = ((size_t)b * SEQ + n0 + n) * CIN + c0 + c4;
    *(uint2*)&Thi[base] = make_uint2((unsigned)h[0] | ((unsigned)h[1] << 16),
                                     (unsigned)h[2] | ((unsigned)h[3] << 16));
    *(uint2*)&Tlo[base] = make_uint2((unsigned)l[0] | ((unsigned)l[1] << 16),
                                     (unsigned)l[2] | ((unsigned)l[3] << 16));
  }
}

// ---------- MFMA GEMM v2, hi/lo split (3-pass) for the three projections.
// Block = 128n x 64o; wave = 32n (2 rowsets) x 64o -> 6 MFMA per 2 LDS reads.
// WA=0: out bf16 [b][n][256]. WA=1: out bf16 [b][o][n] (+bias). ----------
template <int K, bool WA>
__global__ __launch_bounds__(256, 2) void gemm_kernel(
    const u16* __restrict__ Ahi, const u16* __restrict__ Alo,
    const u16* __restrict__ Whi, const u16* __restrict__ Wlo,
    const float* __restrict__ bias, u16* __restrict__ outp) {
  constexpr int SP = K + 8;
  extern __shared__ u16 lds[];  // 64*SP*2 shorts (hi rows then lo rows)
  const int tid = threadIdx.x;
  const int wv = tid >> 6, lane = tid & 63, quad = lane >> 4, ln = lane & 15;
  const int b = blockIdx.x & 7, nt = blockIdx.x >> 3;
  const int o0 = blockIdx.y << 6, n0 = nt << 7;

  constexpr int RW = K / 8;
  for (int i = tid; i < 64 * RW; i += 256) {
    int row = i / RW, kc = (i % RW) * 8;
    *(uint4*)&lds[row * SP + kc] = *(const uint4*)&Whi[(size_t)(o0 + row) * K + kc];
    *(uint4*)&lds[(64 + row) * SP + kc] = *(const uint4*)&Wlo[(size_t)(o0 + row) * K + kc];
  }
  constexpr int NA = K / 32;
  bfrag8 ahi[2][NA], alo[2][NA];
#pragma unroll
  for (int rs = 0; rs < 2; ++rs) {
    const u16* ap = Ahi + ((size_t)b * SEQ + n0 + wv * 32 + rs * 16 + ln) * K + quad * 8;
    const u16* al = Alo + ((size_t)b * SEQ + n0 + wv * 32 + rs * 16 + ln) * K + quad * 8;
#pragma unroll
    for (int a = 0; a < NA; ++a) {
      ahi[rs][a] = *(const bfrag8*)(ap + a * 32);
      alo[rs][a] = *(const bfrag8*)(al + a * 32);
    }
  }
  __syncthreads();

  ffrag4 acc[2][4];
#pragma unroll
  for (int ot = 0; ot < 4; ++ot) {
    ffrag4 e0 = {0.f, 0.f, 0.f, 0.f}, e1 = {0.f, 0.f, 0.f, 0.f};
#pragma unroll
    for (int a = 0; a < NA; ++a) {
      bfrag8 wh = *(const bfrag8*)&lds[(ot * 16 + ln) * SP + a * 32 + quad * 8];
      bfrag8 wl = *(const bfrag8*)&lds[(64 + ot * 16 + ln) * SP + a * 32 + quad * 8];
      if (WA) {
        e0 = MFMA16(wh, ahi[0][a], e0);
        e0 = MFMA16(wh, alo[0][a], e0);
        e0 = MFMA16(wl, ahi[0][a], e0);
        e1 = MFMA16(wh, ahi[1][a], e1);
        e1 = MFMA16(wh, alo[1][a], e1);
        e1 = MFMA16(wl, ahi[1][a], e1);
      } else {
        e0 = MFMA16(ahi[0][a], wh, e0);
        e0 = MFMA16(alo[0][a], wh, e0);
        e0 = MFMA16(ahi[0][a], wl, e0);
        e1 = MFMA16(ahi[1][a], wh, e1);
        e1 = MFMA16(alo[1][a], wh, e1);
        e1 = MFMA16(ahi[1][a], wl, e1);
      }
    }
    acc[0][ot] = e0;
    acc[1][ot] = e1;
  }
  __syncthreads();  // lds free for epilogue

  if (!WA) {
    u16* tl = lds;  // [128 n][72]
#pragma unroll
    for (int rs = 0; rs < 2; ++rs)
#pragma unroll
      for (int ot = 0; ot < 4; ++ot)
#pragma unroll
        for (int r = 0; r < 4; ++r)
          tl[(wv * 32 + rs * 16 + quad * 4 + r) * 72 + ot * 16 + ln] = f2bf(acc[rs][ot][r]);
    __syncthreads();
    for (int i = tid; i < 128 * 8; i += 256) {
      int row = i >> 3, c8 = (i & 7) * 8;
      *(uint4*)&outp[((size_t)b * SEQ + n0 + row) * NC + o0 + c8] = *(uint4*)&tl[row * 72 + c8];
    }
  } else {
    u16* tl = lds;  // [64 o][136]
#pragma unroll
    for (int rs = 0; rs < 2; ++rs)
#pragma unroll
      for (int ot = 0; ot < 4; ++ot)
#pragma unroll
        for (int r = 0; r < 4; ++r)
          tl[(ot * 16 + quad * 4 + r) * 136 + wv * 32 + rs * 16 + ln] = f2bf(acc[rs][ot][r]);
    __syncthreads();
    for (int i = tid; i < 64 * 16; i += 256) {
      int row = i >> 4, n8 = (i & 15) * 8;
      float bb = (bias != nullptr) ? bias[o0 + row] : 0.f;
      u16 pk[8];
#pragma unroll
      for (int j = 0; j < 8; ++j) pk[j] = f2bf(bf2f(tl[row * 136 + n8 + j]) + bb);
      *(uint4*)&outp[((size_t)b * NC + o0 + row) * SEQ + n0 + n8] = *(uint4*)pk;
    }
  }
}

// ---------- rowsum: rowsum_g[b,n] += sum_m exp(e[n,m]) over this block's 512-m quarter ----------
__global__ __launch_bounds__(256, 2) void rowsum_kernel(
    const u16* __restrict__ xqT, const u16* __restrict__ xkT,
    float* __restrict__ rowsum_g) {
  __shared__ u16 bk_l[2][64 * 264];  // 2 x 33792 B
  const int tid = threadIdx.x;
  const int wv = tid >> 6, lane = tid & 63, quad = lane >> 4, ln = lane & 15;
  const int b  = blockIdx.x & 7;
  const int nt = (blockIdx.x >> 3) & 15;
  const int mh = blockIdx.x >> 7;   // 0..3
  const int n0 = nt << 7;
  const int m0 = mh << 9;

  bfrag8 aq[2][8];
#pragma unroll
  for (int rs = 0; rs < 2; ++rs) {
    const u16* qp = xqT + ((size_t)b * SEQ + n0 + wv * 32 + rs * 16 + ln) * NC + quad * 8;
#pragma unroll
    for (int kk = 0; kk < 8; ++kk) aq[rs][kk] = *(const bfrag8*)(qp + kk * 32);
  }

  const int srow = tid >> 2, sseg = tid & 3;
  uint4 pf[8];
  {
    const u16* kp = xkT + ((size_t)b * SEQ + m0 + srow) * NC;
#pragma unroll
    for (int j = 0; j < 8; ++j) pf[j] = *(const uint4*)&kp[(sseg + 4 * j) * 8];
  }

  float rsum[2][4];
#pragma unroll
  for (int rs = 0; rs < 2; ++rs)
#pragma unroll
    for (int r = 0; r < 4; ++r) rsum[rs][r] = 0.f;

  for (int ch = 0; ch < 8; ++ch) {
    u16* buf = bk_l[ch & 1];
#pragma unroll
    for (int j = 0; j < 8; ++j) *(uint4*)&buf[srow * 264 + (sseg + 4 * j) * 8] = pf[j];
    if (ch < 7) {
      const u16* kp = xkT + ((size_t)b * SEQ + m0 + (ch + 1) * 64 + srow) * NC;
#pragma unroll
      for (int j = 0; j < 8; ++j) pf[j] = *(const uint4*)&kp[(sseg + 4 * j) * 8];
    }
    __syncthreads();

    ffrag4 e[2][4];
#pragma unroll
    for (int rs = 0; rs < 2; ++rs)
#pragma unroll
      for (int ms = 0; ms < 4; ++ms) e[rs][ms] = (ffrag4){0.f, 0.f, 0.f, 0.f};
#pragma unroll
    for (int ms = 0; ms < 4; ++ms)
#pragma unroll
      for (int kk = 0; kk < 8; ++kk) {
        bfrag8 bf = *(const bfrag8*)&buf[(ms * 16 + ln) * 264 + kk * 32 + quad * 8];
        e[0][ms] = MFMA16(aq[0][kk], bf, e[0][ms]);
        e[1][ms] = MFMA16(aq[1][kk], bf, e[1][ms]);
      }
#pragma unroll
    for (int rs = 0; rs < 2; ++rs)
#pragma unroll
      for (int ms = 0; ms < 4; ++ms)
#pragma unroll
        for (int r = 0; r < 4; ++r) rsum[rs][r] += __expf(e[rs][ms][r]);
  }

#pragma unroll
  for (int msk = 1; msk < 16; msk <<= 1)
#pragma unroll
    for (int rs = 0; rs < 2; ++rs)
#pragma unroll
      for (int r = 0; r < 4; ++r) rsum[rs][r] += __shfl_xor(rsum[rs][r], msk, 64);
  if (ln == 0) {
#pragma unroll
    for (int rs = 0; rs < 2; ++rs)
#pragma unroll
      for (int r = 0; r < 4; ++r)
        atomicAdd(&rowsum_g[(size_t)b * SEQ + n0 + wv * 32 + rs * 16 + quad * 4 + r],
                  rsum[rs][r]);
  }
}

// ---------- attn: R10 structure + XOR-swizzled p_l + transposed U epilogue.
// U[half][b][m][c] bf16; csum[half][b][m] partials. ----------
__global__ __launch_bounds__(512, 4) void attn_kernel(
    const u16* __restrict__ xqT, const u16* __restrict__ xkT,
    const u16* __restrict__ xv, const float* __restrict__ rowsum_g,
    u16* __restrict__ U, float* __restrict__ csum) {
  __shared__ u16 xq_l[32 * 264];
  __shared__ u16 p_l[64 * 32];    // [row][32], 8B-chunk XOR swizzle by ((row&3)<<1)
  __shared__ float ri_l[32];
  __shared__ float cs_l[64];
  const int tid = threadIdx.x;
  const int wv = tid >> 6, lane = tid & 63, quad = lane >> 4, ln = lane & 15;
  const int b = blockIdx.x & 7;
  const int m0 = ((blockIdx.x >> 3) & 31) << 6;
  const int half = blockIdx.x >> 8;
  const int nsub = wv & 1, msub = wv >> 1;
  const int nt0 = half * 32, ntEnd = nt0 + 32;
  const int swz = (ln & 3) << 1;

  if (tid < 64) cs_l[tid] = 0.f;

  // persistent energy B-frags: keys m0 + msub*16 + ln, K=256
  bfrag8 bk[8];
  {
    const u16* kp = xkT + ((size_t)b * SEQ + m0 + msub * 16 + ln) * NC + quad * 8;
#pragma unroll
    for (int kk = 0; kk < 8; ++kk) bk[kk] = *(const bfrag8*)(kp + kk * 32);
  }

  // prefetch state: xq tile (32B/thread), rowsum, and this wave's xv frags
  const int prow = tid >> 4, pcol = (tid & 15) << 4;
  uint4 pf0, pf1;
  float rspf = 1.f;
  bfrag8 avpf0, avpf1;
  {
    const int n0 = nt0 << 5;
    const u16* src = &xqT[((size_t)b * SEQ + n0 + prow) * NC + pcol];
    pf0 = *(const uint4*)src;
    pf1 = *(const uint4*)(src + 8);
    if (tid < 32) rspf = rowsum_g[(size_t)b * SEQ + n0 + tid];
    const u16* vp = &xv[((size_t)b * NC + wv * 32 + ln) * SEQ + n0 + quad * 8];
    avpf0 = *(const bfrag8*)vp;
    avpf1 = *(const bfrag8*)(vp + 16 * SEQ);
  }

  ffrag4 acc[2][4];
#pragma unroll
  for (int ct = 0; ct < 2; ++ct)
#pragma unroll
    for (int s = 0; s < 4; ++s) acc[ct][s] = (ffrag4){0.f, 0.f, 0.f, 0.f};
  float cs = 0.f;

  for (int nt = nt0; nt < ntEnd; ++nt) {
    // (a) commit prefetched data to LDS / regs
    bfrag8 av0 = avpf0, av1 = avpf1;
    *(uint4*)&xq_l[prow * 264 + pcol] = pf0;
    *(uint4*)&xq_l[prow * 264 + pcol + 8] = pf1;
    if (tid < 32) ri_l[tid] = 1.0f / rspf;
    // (b) issue next iteration's loads
    {
      const int ntn = (nt + 1 < ntEnd) ? nt + 1 : nt;
      const int n0n = ntn << 5;
      const u16* src = &xqT[((size_t)b * SEQ + n0n + prow) * NC + pcol];
      pf0 = *(const uint4*)src;
      pf1 = *(const uint4*)(src + 8);
      if (tid < 32) rspf = rowsum_g[(size_t)b * SEQ + n0n + tid];
      const u16* vp = &xv[((size_t)b * NC + wv * 32 + ln) * SEQ + n0n + quad * 8];
      avpf0 = *(const bfrag8*)vp;
      avpf1 = *(const bfrag8*)(vp + 16 * SEQ);
    }
    __syncthreads();
    // (d) E-phase
    {
      ffrag4 e = {0.f, 0.f, 0.f, 0.f};
#pragma unroll
      for (int kk = 0; kk < 8; ++kk) {
        bfrag8 a = *(const bfrag8*)&xq_l[(nsub * 16 + ln) * 264 + kk * 32 + quad * 8];
        e = MFMA16(a, bk[kk], e);
      }
      u16 pu[4];
#pragma unroll
      for (int r = 0; r < 4; ++r) {
        float p = __expf(e[r]) * ri_l[nsub * 16 + quad * 4 + r];
        cs += p;
        pu[r] = f2bf(p);
      }
      // logical 8B chunk (4*nsub + quad) of row (msub*16+ln), XOR-swizzled
      *(uint2*)&p_l[(msub * 16 + ln) * 32 + (((4 * nsub + quad) ^ swz) << 2)] =
          make_uint2((unsigned)pu[0] | ((unsigned)pu[1] << 16),
                     (unsigned)pu[2] | ((unsigned)pu[3] << 16));
    }
    __syncthreads();
    // (f) PV: 16B read = logical chunks (2q, 2q+1) of row (s*16+ln), swizzled
#pragma unroll
    for (int s = 0; s < 4; ++s) {
      bfrag8 pb = *(const bfrag8*)&p_l[(s * 16 + ln) * 32 + (((2 * quad) ^ swz) << 2)];
      acc[0][s] = MFMA16(av0, pb, acc[0][s]);
      acc[1][s] = MFMA16(av1, pb, acc[1][s]);
    }
  }

  cs += __shfl_down(cs, 32, 64);
  cs += __shfl_down(cs, 16, 64);
  if (lane < 16) atomicAdd(&cs_l[msub * 16 + ln], cs);
  __syncthreads();
  if (tid < 64) csum[((size_t)half * NB + b) * SEQ + m0 + tid] = cs_l[tid];

  // transposed epilogue: U[half][b][m][c], lane writes 4 consecutive c (uint2)
  u16* Uh = U + (size_t)half * NB * SEQ * NC;
#pragma unroll
  for (int ct = 0; ct < 2; ++ct)
#pragma unroll
    for (int s = 0; s < 4; ++s) {
      u16 pk[4];
#pragma unroll
      for (int r = 0; r < 4; ++r) pk[r] = f2bf(acc[ct][s][r]);
      *(uint2*)&Uh[((size_t)b * SEQ + m0 + s * 16 + ln) * NC + wv * 32 + ct * 16 + quad * 4] =
          make_uint2((unsigned)pk[0] | ((unsigned)pk[1] << 16),
                     (unsigned)pk[2] | ((unsigned)pk[3] << 16));
    }
}

// ---------- gemm_t: y[b][o][n] = Wt·x_r + bt with x_r = (U0+U1)·invcol fused in A-load.
// 2-pass hi/lo on W only; accumulates BN partial sums. ----------
__global__ __launch_bounds__(256, 2) void gemmt_kernel(
    const u16* __restrict__ U, const float* __restrict__ csum,
    const u16* __restrict__ Whi, const u16* __restrict__ Wlo,
    const float* __restrict__ bias, float* __restrict__ outp,
    float* __restrict__ ssum, float* __restrict__ sqsum) {
  constexpr int K = NC, SP = K + 8;
  __shared__ u16 lds[128 * SP];  // 67584 B (hi rows then lo rows)
  __shared__ float bsum[64], bsq[64];
  const int tid = threadIdx.x;
  const int wv = tid >> 6, lane = tid & 63, quad = lane >> 4, ln = lane & 15;
  const int b = blockIdx.x & 7, nt = blockIdx.x >> 3;
  const int o0 = blockIdx.y << 6, n0 = nt << 7;
  const size_t SZu = (size_t)NB * SEQ * NC;

  if (tid < 64) { bsum[tid] = 0.f; bsq[tid] = 0.f; }

  for (int i = tid; i < 64 * 32; i += 256) {
    int row = i >> 5, kc = (i & 31) * 8;
    *(uint4*)&lds[row * SP + kc] = *(const uint4*)&Whi[(size_t)(o0 + row) * K + kc];
    *(uint4*)&lds[(64 + row) * SP + kc] = *(const uint4*)&Wlo[(size_t)(o0 + row) * K + kc];
  }

  // A-frags: x_r rows = (U0+U1)*invcol, bf16
  bfrag8 af[2][8];
#pragma unroll
  for (int rs = 0; rs < 2; ++rs) {
    const int row = n0 + wv * 32 + rs * 16 + ln;
    const float ic = 1.0f / (1e-9f + csum[(size_t)b * SEQ + row] +
                             csum[((size_t)NB + b) * SEQ + row]);
    const u16* up = U + ((size_t)b * SEQ + row) * NC + quad * 8;
#pragma unroll
    for (int a = 0; a < 8; ++a) {
      bfrag8 u0 = *(const bfrag8*)(up + a * 32);
      bfrag8 u1 = *(const bfrag8*)(up + SZu + a * 32);
      union { u16 u[8]; bfrag8 f; } t;
#pragma unroll
      for (int j = 0; j < 8; ++j)
        t.u[j] = f2bf((bf2f((u16)u0[j]) + bf2f((u16)u1[j])) * ic);
      af[rs][a] = t.f;
    }
  }
  __syncthreads();

  ffrag4 acc[2][4];
#pragma unroll
  for (int ot = 0; ot < 4; ++ot) {
    ffrag4 e0 = {0.f, 0.f, 0.f, 0.f}, e1 = {0.f, 0.f, 0.f, 0.f};
#pragma unroll
    for (int a = 0; a < 8; ++a) {
      bfrag8 wh = *(const bfrag8*)&lds[(ot * 16 + ln) * SP + a * 32 + quad * 8];
      bfrag8 wl = *(const bfrag8*)&lds[(64 + ot * 16 + ln) * SP + a * 32 + quad * 8];
      e0 = MFMA16(wh, af[0][a], e0);
      e0 = MFMA16(wl, af[0][a], e0);
      e1 = MFMA16(wh, af[1][a], e1);
      e1 = MFMA16(wl, af[1][a], e1);
    }
    acc[0][ot] = e0;
    acc[1][ot] = e1;
  }
  __syncthreads();

  float* fl = (float*)lds;  // [64 o][132]
#pragma unroll
  for (int rs = 0; rs < 2; ++rs)
#pragma unroll
    for (int ot = 0; ot < 4; ++ot)
#pragma unroll
      for (int r = 0; r < 4; ++r)
        fl[(ot * 16 + quad * 4 + r) * 132 + wv * 32 + rs * 16 + ln] = acc[rs][ot][r];
  __syncthreads();
  for (int i = tid; i < 64 * 32; i += 256) {
    int row = i >> 5, n4 = (i & 31) * 4;
    float bb = (bias != nullptr) ? bias[o0 + row] : 0.f;
    const float* src = &fl[row * 132 + n4];
    float4 v = *(const float4*)src;
    v.x += bb; v.y += bb; v.z += bb; v.w += bb;
    *(float4*)&outp[((size_t)b * NC + o0 + row) * SEQ + n0 + n4] = v;
    float s = v.x + v.y + v.z + v.w;
    float sq = v.x * v.x + v.y * v.y + v.z * v.z + v.w * v.w;
    atomicAdd(&bsum[row], s);
    atomicAdd(&bsq[row], sq);
  }
  __syncthreads();
  if (tid < 64) {
    atomicAdd(&ssum[o0 + tid], bsum[tid]);
    atomicAdd(&sqsum[o0 + tid], bsq[tid]);
  }
}

// ---------- BN normalize + ReLU ----------
__global__ __launch_bounds__(256) void bnorm_kernel(
    const float* __restrict__ y, const float* __restrict__ ssum, const float* __restrict__ sqsum,
    const float* __restrict__ gamma, const float* __restrict__ beta, float* __restrict__ out) {
  size_t e0 = ((size_t)blockIdx.x * 256 + threadIdx.x) * 4;
  int o = (int)((e0 >> 11) & (NC - 1));
  const float invn = 1.0f / 16384.0f;
  float mean = ssum[o] * invn;
  float var = sqsum[o] * invn - mean * mean;
  float rs = rsqrtf(var + 1e-5f);
  float a = gamma[o] * rs;
  float c = beta[o] - mean * a;
  float4 v = *(const float4*)(y + e0);
  float4 r;
  r.x = fmaxf(0.f, fmaf(v.x, a, c));
  r.y = fmaxf(0.f, fmaf(v.y, a, c));
  r.z = fmaxf(0.f, fmaf(v.z, a, c));
  r.w = fmaxf(0.f, fmaf(v.w, a, c));
  *(float4*)(out + e0) = r;
}

extern "C" void kernel_launch(void* const* d_in, const int* in_sizes, int n_in,
                              void* d_out, int out_size, void* d_ws, size_t ws_size,
                              hipStream_t stream) {
  const float* q     = (const float*)d_in[0];
  const float* x     = (const float*)d_in[1];
  const float* Wq    = (const float*)d_in[2];
  const float* Wk    = (const float*)d_in[3];
  const float* Wv    = (const float*)d_in[4];
  const float* bv    = (const float*)d_in[5];
  const float* Wt    = (const float*)d_in[6];
  const float* bt    = (const float*)d_in[7];
  const float* gamma = (const float*)d_in[8];
  const float* beta  = (const float*)d_in[9];
  float* out = (float*)d_out;

  // Arena (phase-overlaid). SZ = 4,194,304 elems; SZB = 16 MB.
  // [0,16M):  qT hi/lo      -> later U half0 [B][M][C]
  // [16,20M): xT hi/lo      -> later part of U half1
  // [0,32M):  U [2][B][M][C] bf16 (after projections)
  // [32,40M): xqT bf16 [B][N][C]   -> later y fp32 [B][C][N] at [32,48M)
  // [40,48M): xkT bf16 [B][M][C]
  // [48,56M): xv bf16 [B][C][N]
  // [56M+):   wpack, rowsum_g, csum, ssum/sqsum
  const size_t SZ = (size_t)NB * NC * SEQ;
  const size_t SZB = SZ * 4;
  char* wsb = (char*)d_ws;
  u16* qT_hi = (u16*)(wsb);
  u16* qT_lo = qT_hi + SZ;
  u16* xT_hi = (u16*)(wsb + SZB);
  u16* xT_lo = xT_hi + SZ / 4;
  u16* U     = (u16*)(wsb);                 // [2][B][SEQ][NC]
  u16* xqT = (u16*)(wsb + 2 * SZB);
  u16* xkT = xqT + SZ;
  u16* xv = (u16*)(wsb + 3 * SZB);
  float* y = (float*)(wsb + 2 * SZB);       // overlays xqT/xkT (dead at gemm_t)
  u16* wpack = (u16*)(wsb + 3 * SZB + SZB / 2);
  u16* Wq_hi = wpack,          *Wq_lo = wpack + 65536;
  u16* Wv_hi = wpack + 131072, *Wv_lo = wpack + 196608;
  u16* Wt_hi = wpack + 262144, *Wt_lo = wpack + 327680;
  u16* Wk_hi = wpack + 393216, *Wk_lo = wpack + 409600;
  float* rowsum_g = (float*)(wpack + 425984);     // [B][SEQ]
  float* csum = rowsum_g + (size_t)NB * SEQ;      // [2][B][SEQ]
  float* ssum = csum + 2 * (size_t)NB * SEQ;      // [256]
  float* sqsum = ssum + NC;                       // [256]

  wconv_kernel<<<897, 256, 0, stream>>>(Wq, Wv, Wt, Wk, wpack, ssum, rowsum_g);
  tconv_kernel<NC><<<dim3(64, 64), 256, 0, stream>>>(q, qT_hi, qT_lo);
  tconv_kernel<NCK><<<dim3(16, 64), 256, 0, stream>>>(x, xT_hi, xT_lo);

  const size_t shm256 = 64 * (256 + 8) * 2 * sizeof(u16);  // 67,584 B
  const size_t shm64  = 64 * (64 + 8) * 2 * sizeof(u16);   // 18,432 B
  gemm_kernel<256, false><<<dim3(128, 4), 256, shm256, stream>>>(
      qT_hi, qT_lo, Wq_hi, Wq_lo, nullptr, xqT);
  gemm_kernel<64, false><<<dim3(128, 4), 256, shm64, stream>>>(
      xT_hi, xT_lo, Wk_hi, Wk_lo, nullptr, xkT);
  gemm_kernel<256, true><<<dim3(128, 4), 256, shm256, stream>>>(
      qT_hi, qT_lo, Wv_hi, Wv_lo, bv, xv);

  rowsum_kernel<<<512, 256, 0, stream>>>(xqT, xkT, rowsum_g);
  attn_kernel<<<512, 512, 0, stream>>>(xqT, xkT, xv, rowsum_g, U, csum);
  gemmt_kernel<<<dim3(128, 4), 256, 0, stream>>>(
      U, csum, Wt_hi, Wt_lo, bt, y, ssum, sqsum);

  bnorm_kernel<<<4096, 256, 0, stream>>>(y, ssum, sqsum, gamma, beta, out);
}